// Round 1
// baseline (207.562 us; speedup 1.0000x reference)
//
#include <hip/hip_runtime.h>
#include <hip/hip_bf16.h>

// out = x @ (W + 16*(M@N))^T + b  where M(1024x8), N(8x1024) are folded TT cores.
// x:(16384,1024) fp32. Single bf16-MFMA GEMM after two tiny setup kernels.

#define D_DIM 1024
#define BS_ROWS 16384
#define ALPHA_F 16.0f
#define BM 128
#define BN 128
#define BK 32

using bf16   = __bf16;
using bf16x8 = __attribute__((ext_vector_type(8))) __bf16;
using bf16x4 = __attribute__((ext_vector_type(4))) __bf16;
using f32x4  = __attribute__((ext_vector_type(4))) float;

#define GPTR(p) (const __attribute__((address_space(1))) void*)(p)
#define SPTR(p) (__attribute__((address_space(3))) void*)(p)

// ---- Kernel A: fold TT cores into M[1024][8] and N[8][1024] -----------------
__global__ void fold_cores_kernel(const float* __restrict__ c0,
                                  const float* __restrict__ c1,
                                  const float* __restrict__ c2,
                                  const float* __restrict__ c3,
                                  const float* __restrict__ c4,
                                  const float* __restrict__ c5,
                                  float* __restrict__ Mmat,   // [1024][8]
                                  float* __restrict__ Nmat)   // [8][1024]
{
    __shared__ float tmp[1024];
    const int tid = threadIdx.x;  // 256 threads

    // Phase 1: tmp[(i2*8+i1)*1 ... ] = t2[i2i1][p2] = sum_p1 c0[0,i1,p1]*c1[p1,i2,p2]
    for (int e = tid; e < 1024; e += 256) {
        int p2 = e & 7, i2i1 = e >> 3;
        int i1 = i2i1 & 7, i2 = i2i1 >> 3;
        float s = 0.f;
        for (int p1 = 0; p1 < 8; ++p1)
            s += c0[i1 * 8 + p1] * c1[p1 * 128 + i2 * 8 + p2];
        tmp[e] = s;
    }
    __syncthreads();
    // Phase 2: M[d][p3] = sum_p2 t2[i2*8+i1][p2] * c2[p2,i3,p3], d=i3*128+i2*8+i1
    for (int e = tid; e < 8192; e += 256) {
        int p3 = e & 7, d = e >> 3;
        int i1 = d & 7, i2 = (d >> 3) & 15, i3 = d >> 7;
        float s = 0.f;
        for (int p2 = 0; p2 < 8; ++p2)
            s += tmp[(i2 * 8 + i1) * 8 + p2] * c2[p2 * 64 + i3 * 8 + p3];
        Mmat[e] = s;
    }
    __syncthreads();
    // Phase 3: tmp[p4*128+nn] = v[p4][n2*8+n3] = sum_p5 c4[p4,n2,p5]*c5[p5,n3,0]
    for (int e = tid; e < 1024; e += 256) {
        int nn = e & 127, p4 = e >> 7;
        int n3 = nn & 7, n2 = nn >> 3;
        float s = 0.f;
        for (int p5 = 0; p5 < 8; ++p5)
            s += c4[p4 * 128 + n2 * 8 + p5] * c5[p5 * 8 + n3];
        tmp[e] = s;
    }
    __syncthreads();
    // Phase 4: N[r3][o] = sum_p4 c3[r3,n1,p4]*v[p4][nn], o = n1*128 + nn
    for (int e = tid; e < 8192; e += 256) {
        int o = e & 1023, r3 = e >> 10;
        int n1 = o >> 7, nn = o & 127;
        float s = 0.f;
        for (int p4 = 0; p4 < 8; ++p4)
            s += c3[r3 * 64 + n1 * 8 + p4] * tmp[p4 * 128 + nn];
        Nmat[e] = s;
    }
}

// ---- Kernel B: Weff[o][d] = bf16( W[o][d] + 16 * sum_r M[d][r]*N[r][o] ) ----
__global__ void build_weff_kernel(const float* __restrict__ W,
                                  const float* __restrict__ Mmat,
                                  const float* __restrict__ Nmat,
                                  bf16* __restrict__ Weff)
{
    int idx = (blockIdx.x * 256 + threadIdx.x) * 4;  // 4 consecutive d, same o
    int o = idx >> 10;
    int d0 = idx & 1023;
    f32x4 w = *(const f32x4*)&W[idx];
    bf16x4 v;
    for (int k = 0; k < 4; ++k) {
        float acc = 0.f;
        for (int r = 0; r < 8; ++r)
            acc += Mmat[(d0 + k) * 8 + r] * Nmat[r * 1024 + o];
        v[k] = (bf16)(w[k] + ALPHA_F * acc);
    }
    *(bf16x4*)&Weff[idx] = v;
}

// ---- Kernel C: 16384x1024x1024 bf16 MFMA GEMM + bias ------------------------
// A = x (fp32, converted during LDS staging), B = Weff (bf16, [o][d] K-contig,
// staged via global_load_lds width 16), C = fp32 out.
__global__ __launch_bounds__(256) void gemm_bias_kernel(
    const float* __restrict__ X,
    const bf16* __restrict__ Weff,
    const float* __restrict__ bias,
    float* __restrict__ Out)
{
    __shared__ __align__(16) bf16 As[BM][BK];  // 8 KB
    __shared__ __align__(16) bf16 Bs[BN][BK];  // 8 KB

    const int tid  = threadIdx.x;
    const int wave = tid >> 6, lane = tid & 63;
    const int mtile = blockIdx.x, ntile = blockIdx.y;
    const int wr = wave >> 1, wc = wave & 1;
    const int l15 = lane & 15, quad = lane >> 4;

    // A staging: thread t handles row (t>>1), 16-float half (t&1)
    const int ar = tid >> 1, ah = tid & 1;
    const float* xsrc = X + (size_t)(mtile * BM + ar) * D_DIM + ah * 16;
    bf16* adst = &As[ar][ah * 16];

    // B staging via global_load_lds: wave w issue j covers LDS bytes
    // [(w*2+j)*1024, +1024): rows (w*2+j)*16 + lane/4, k-offset (lane&3)*8
    const bf16* bsrc0 = Weff + (size_t)(ntile * BN + wave * 32 + (lane >> 2)) * D_DIM
                        + (lane & 3) * 8;
    const bf16* bsrc1 = bsrc0 + 16 * D_DIM;
    char* bbase = (char*)&Bs[0][0];
    void* bdst0 = bbase + wave * 2048;
    void* bdst1 = bbase + wave * 2048 + 1024;

    f32x4 acc[4][4];
    for (int i = 0; i < 4; ++i)
        for (int j = 0; j < 4; ++j)
            for (int r = 0; r < 4; ++r) acc[i][j][r] = 0.f;

    for (int kt = 0; kt < D_DIM / BK; ++kt) {
        // B: async global->LDS (16B per lane, wave-uniform LDS base)
        __builtin_amdgcn_global_load_lds(GPTR(bsrc0 + kt * BK), SPTR(bdst0), 16, 0, 0);
        __builtin_amdgcn_global_load_lds(GPTR(bsrc1 + kt * BK), SPTR(bdst1), 16, 0, 0);

        // A: load 16 fp32, convert to bf16, 2x ds_write_b128
        const f32x4* xp = (const f32x4*)(xsrc + kt * BK);
        f32x4 f0 = xp[0], f1 = xp[1], f2 = xp[2], f3 = xp[3];
        bf16x8 p0, p1;
        p0[0] = (bf16)f0[0]; p0[1] = (bf16)f0[1]; p0[2] = (bf16)f0[2]; p0[3] = (bf16)f0[3];
        p0[4] = (bf16)f1[0]; p0[5] = (bf16)f1[1]; p0[6] = (bf16)f1[2]; p0[7] = (bf16)f1[3];
        p1[0] = (bf16)f2[0]; p1[1] = (bf16)f2[1]; p1[2] = (bf16)f2[2]; p1[3] = (bf16)f2[3];
        p1[4] = (bf16)f3[0]; p1[5] = (bf16)f3[1]; p1[6] = (bf16)f3[2]; p1[7] = (bf16)f3[3];
        *(bf16x8*)adst = p0;
        *(bf16x8*)(adst + 8) = p1;

        __syncthreads();

        bf16x8 af[4], bfr[4];
        for (int i = 0; i < 4; ++i)
            af[i] = *(const bf16x8*)&As[wr * 64 + i * 16 + l15][quad * 8];
        for (int j = 0; j < 4; ++j)
            bfr[j] = *(const bf16x8*)&Bs[wc * 64 + j * 16 + l15][quad * 8];
        for (int i = 0; i < 4; ++i)
            for (int j = 0; j < 4; ++j)
                acc[i][j] = __builtin_amdgcn_mfma_f32_16x16x32_bf16(
                    af[i], bfr[j], acc[i][j], 0, 0, 0);

        __syncthreads();
    }

    // Epilogue: C/D layout col = lane&15, row = quad*4 + reg
    float bj[4];
    for (int j = 0; j < 4; ++j)
        bj[j] = bias[ntile * BN + wc * 64 + j * 16 + l15];
    for (int i = 0; i < 4; ++i) {
        int row0 = mtile * BM + wr * 64 + i * 16 + quad * 4;
        for (int r = 0; r < 4; ++r) {
            float* orow = Out + (size_t)(row0 + r) * D_DIM + ntile * BN + wc * 64 + l15;
            for (int j = 0; j < 4; ++j)
                orow[j * 16] = acc[i][j][r] + bj[j];
        }
    }
}

extern "C" void kernel_launch(void* const* d_in, const int* in_sizes, int n_in,
                              void* d_out, int out_size, void* d_ws, size_t ws_size,
                              hipStream_t stream) {
    const float* x  = (const float*)d_in[0];
    const float* W  = (const float*)d_in[1];
    const float* b  = (const float*)d_in[2];
    const float* c0 = (const float*)d_in[3];
    const float* c1 = (const float*)d_in[4];
    const float* c2 = (const float*)d_in[5];
    const float* c3 = (const float*)d_in[6];
    const float* c4 = (const float*)d_in[7];
    const float* c5 = (const float*)d_in[8];
    float* out = (float*)d_out;

    // Workspace layout: Weff bf16 2MB | M 32KB | N 32KB  (total ~2.06 MB)
    char* ws = (char*)d_ws;
    bf16*  Weff = (bf16*)ws;
    float* Mmat = (float*)(ws + 2u * 1024u * 1024u);
    float* Nmat = (float*)(ws + 2u * 1024u * 1024u + 32u * 1024u);

    fold_cores_kernel<<<1, 256, 0, stream>>>(c0, c1, c2, c3, c4, c5, Mmat, Nmat);
    build_weff_kernel<<<1024, 256, 0, stream>>>(W, Mmat, Nmat, Weff);
    dim3 grid(BS_ROWS / BM, D_DIM / BN);
    gemm_bias_kernel<<<grid, 256, 0, stream>>>(x, Weff, b, out);
}

// Round 2
// 191.290 us; speedup vs baseline: 1.0851x; 1.0851x over previous
//
#include <hip/hip_runtime.h>
#include <hip/hip_bf16.h>

// out = x @ (W + 16*(M@N))^T + b  where M(1024x8), N(8x1024) are folded TT cores.
// x:(16384,1024) fp32. Pipeline: fold cores -> build Weff(bf16) -> cast x to bf16
// -> m97-style bf16 MFMA GEMM (both operands via global_load_lds width-16).

#define D_DIM 1024
#define BS_ROWS 16384
#define ALPHA_F 16.0f
#define BM 128
#define BN 128
#define BK 32

using bf16   = __bf16;
using bf16x8 = __attribute__((ext_vector_type(8))) __bf16;
using bf16x4 = __attribute__((ext_vector_type(4))) __bf16;
using f32x4  = __attribute__((ext_vector_type(4))) float;

#define GPTR(p) (const __attribute__((address_space(1))) void*)(p)
#define SPTR(p) (__attribute__((address_space(3))) void*)(p)

// ---- Kernel A: fold TT cores into M[1024][8] and N[8][1024] -----------------
__global__ void fold_cores_kernel(const float* __restrict__ c0,
                                  const float* __restrict__ c1,
                                  const float* __restrict__ c2,
                                  const float* __restrict__ c3,
                                  const float* __restrict__ c4,
                                  const float* __restrict__ c5,
                                  float* __restrict__ Mmat,   // [1024][8]
                                  float* __restrict__ Nmat)   // [8][1024]
{
    __shared__ float tmp[1024];
    const int tid = threadIdx.x;  // 256 threads

    for (int e = tid; e < 1024; e += 256) {
        int p2 = e & 7, i2i1 = e >> 3;
        int i1 = i2i1 & 7, i2 = i2i1 >> 3;
        float s = 0.f;
        for (int p1 = 0; p1 < 8; ++p1)
            s += c0[i1 * 8 + p1] * c1[p1 * 128 + i2 * 8 + p2];
        tmp[e] = s;
    }
    __syncthreads();
    for (int e = tid; e < 8192; e += 256) {
        int p3 = e & 7, d = e >> 3;
        int i1 = d & 7, i2 = (d >> 3) & 15, i3 = d >> 7;
        float s = 0.f;
        for (int p2 = 0; p2 < 8; ++p2)
            s += tmp[(i2 * 8 + i1) * 8 + p2] * c2[p2 * 64 + i3 * 8 + p3];
        Mmat[e] = s;
    }
    __syncthreads();
    for (int e = tid; e < 1024; e += 256) {
        int nn = e & 127, p4 = e >> 7;
        int n3 = nn & 7, n2 = nn >> 3;
        float s = 0.f;
        for (int p5 = 0; p5 < 8; ++p5)
            s += c4[p4 * 128 + n2 * 8 + p5] * c5[p5 * 8 + n3];
        tmp[e] = s;
    }
    __syncthreads();
    for (int e = tid; e < 8192; e += 256) {
        int o = e & 1023, r3 = e >> 10;
        int n1 = o >> 7, nn = o & 127;
        float s = 0.f;
        for (int p4 = 0; p4 < 8; ++p4)
            s += c3[r3 * 64 + n1 * 8 + p4] * tmp[p4 * 128 + nn];
        Nmat[e] = s;
    }
}

// ---- Kernel B: Weff[o][d] = bf16( W[o][d] + 16 * sum_r M[d][r]*N[r][o] ) ----
__global__ void build_weff_kernel(const float* __restrict__ W,
                                  const float* __restrict__ Mmat,
                                  const float* __restrict__ Nmat,
                                  bf16* __restrict__ Weff)
{
    int idx = (blockIdx.x * 256 + threadIdx.x) * 4;  // 4 consecutive d, same o
    int o = idx >> 10;
    int d0 = idx & 1023;
    f32x4 w = *(const f32x4*)&W[idx];
    bf16x4 v;
    for (int k = 0; k < 4; ++k) {
        float acc = 0.f;
        for (int r = 0; r < 8; ++r)
            acc += Mmat[(d0 + k) * 8 + r] * Nmat[r * 1024 + o];
        v[k] = (bf16)(w[k] + ALPHA_F * acc);
    }
    *(bf16x4*)&Weff[idx] = v;
}

// ---- Kernel B2: cast x (fp32) -> xb (bf16), streaming -----------------------
__global__ void cast_x_kernel(const float* __restrict__ X, bf16* __restrict__ Xb)
{
    int i = (blockIdx.x * 256 + threadIdx.x) * 8;
    f32x4 a = *(const f32x4*)&X[i];
    f32x4 b = *(const f32x4*)&X[i + 4];
    bf16x8 v;
    v[0] = (bf16)a[0]; v[1] = (bf16)a[1]; v[2] = (bf16)a[2]; v[3] = (bf16)a[3];
    v[4] = (bf16)b[0]; v[5] = (bf16)b[1]; v[6] = (bf16)b[2]; v[7] = (bf16)b[3];
    *(bf16x8*)&Xb[i] = v;
}

// ---- Kernel C: 16384x1024x1024 bf16 MFMA GEMM + bias (m97 structure) --------
// Both operands bf16 K-contiguous, staged via global_load_lds width 16.
__global__ __launch_bounds__(256) void gemm_bb_kernel(
    const bf16* __restrict__ Xb,
    const bf16* __restrict__ Weff,
    const float* __restrict__ bias,
    float* __restrict__ Out)
{
    __shared__ __align__(16) bf16 As[BM][BK];  // 8 KB
    __shared__ __align__(16) bf16 Bs[BN][BK];  // 8 KB

    const int tid  = threadIdx.x;
    const int wave = tid >> 6, lane = tid & 63;
    const int mtile = blockIdx.x, ntile = blockIdx.y;
    const int wr = wave >> 1, wc = wave & 1;
    const int l15 = lane & 15, quad = lane >> 4;

    // Staging: wave w, issue j -> LDS bytes [(w*2+j)*1024, +1024)
    // = rows (w*2+j)*16 + lane/4, k-offset (lane&3)*8 elements (16 B).
    const int srow = wave * 32 + (lane >> 2);
    const int skof = (lane & 3) * 8;
    const bf16* asrc0 = Xb  + (size_t)(mtile * BM + srow) * D_DIM + skof;
    const bf16* asrc1 = asrc0 + 16 * D_DIM;
    const bf16* bsrc0 = Weff + (size_t)(ntile * BN + srow) * D_DIM + skof;
    const bf16* bsrc1 = bsrc0 + 16 * D_DIM;
    char* abase = (char*)&As[0][0];
    char* bbase = (char*)&Bs[0][0];
    void* adst0 = abase + wave * 2048;
    void* adst1 = abase + wave * 2048 + 1024;
    void* bdst0 = bbase + wave * 2048;
    void* bdst1 = bbase + wave * 2048 + 1024;

    f32x4 acc[4][4];
    for (int i = 0; i < 4; ++i)
        for (int j = 0; j < 4; ++j)
            for (int r = 0; r < 4; ++r) acc[i][j][r] = 0.f;

    for (int kt = 0; kt < D_DIM / BK; ++kt) {
        const int ko = kt * BK;
        __builtin_amdgcn_global_load_lds(GPTR(asrc0 + ko), SPTR(adst0), 16, 0, 0);
        __builtin_amdgcn_global_load_lds(GPTR(asrc1 + ko), SPTR(adst1), 16, 0, 0);
        __builtin_amdgcn_global_load_lds(GPTR(bsrc0 + ko), SPTR(bdst0), 16, 0, 0);
        __builtin_amdgcn_global_load_lds(GPTR(bsrc1 + ko), SPTR(bdst1), 16, 0, 0);

        __syncthreads();

        bf16x8 af[4], bfr[4];
        for (int i = 0; i < 4; ++i)
            af[i] = *(const bf16x8*)&As[wr * 64 + i * 16 + l15][quad * 8];
        for (int j = 0; j < 4; ++j)
            bfr[j] = *(const bf16x8*)&Bs[wc * 64 + j * 16 + l15][quad * 8];
        for (int i = 0; i < 4; ++i)
            for (int j = 0; j < 4; ++j)
                acc[i][j] = __builtin_amdgcn_mfma_f32_16x16x32_bf16(
                    af[i], bfr[j], acc[i][j], 0, 0, 0);

        __syncthreads();
    }

    // Epilogue: C/D layout col = lane&15, row = quad*4 + reg
    float bj[4];
    for (int j = 0; j < 4; ++j)
        bj[j] = bias[ntile * BN + wc * 64 + j * 16 + l15];
    for (int i = 0; i < 4; ++i) {
        int row0 = mtile * BM + wr * 64 + i * 16 + quad * 4;
        for (int r = 0; r < 4; ++r) {
            float* orow = Out + (size_t)(row0 + r) * D_DIM + ntile * BN + wc * 64 + l15;
            for (int j = 0; j < 4; ++j)
                orow[j * 16] = acc[i][j][r] + bj[j];
        }
    }
}

// ---- Fallback GEMM (fp32 A staged via VALU convert) — used if ws too small --
__global__ __launch_bounds__(256) void gemm_bias_kernel(
    const float* __restrict__ X,
    const bf16* __restrict__ Weff,
    const float* __restrict__ bias,
    float* __restrict__ Out)
{
    __shared__ __align__(16) bf16 As[BM][BK];
    __shared__ __align__(16) bf16 Bs[BN][BK];

    const int tid  = threadIdx.x;
    const int wave = tid >> 6, lane = tid & 63;
    const int mtile = blockIdx.x, ntile = blockIdx.y;
    const int wr = wave >> 1, wc = wave & 1;
    const int l15 = lane & 15, quad = lane >> 4;

    const int ar = tid >> 1, ah = tid & 1;
    const float* xsrc = X + (size_t)(mtile * BM + ar) * D_DIM + ah * 16;
    bf16* adst = &As[ar][ah * 16];

    const bf16* bsrc0 = Weff + (size_t)(ntile * BN + wave * 32 + (lane >> 2)) * D_DIM
                        + (lane & 3) * 8;
    const bf16* bsrc1 = bsrc0 + 16 * D_DIM;
    char* bbase = (char*)&Bs[0][0];
    void* bdst0 = bbase + wave * 2048;
    void* bdst1 = bbase + wave * 2048 + 1024;

    f32x4 acc[4][4];
    for (int i = 0; i < 4; ++i)
        for (int j = 0; j < 4; ++j)
            for (int r = 0; r < 4; ++r) acc[i][j][r] = 0.f;

    for (int kt = 0; kt < D_DIM / BK; ++kt) {
        __builtin_amdgcn_global_load_lds(GPTR(bsrc0 + kt * BK), SPTR(bdst0), 16, 0, 0);
        __builtin_amdgcn_global_load_lds(GPTR(bsrc1 + kt * BK), SPTR(bdst1), 16, 0, 0);

        const f32x4* xp = (const f32x4*)(xsrc + kt * BK);
        f32x4 f0 = xp[0], f1 = xp[1], f2 = xp[2], f3 = xp[3];
        bf16x8 p0, p1;
        p0[0] = (bf16)f0[0]; p0[1] = (bf16)f0[1]; p0[2] = (bf16)f0[2]; p0[3] = (bf16)f0[3];
        p0[4] = (bf16)f1[0]; p0[5] = (bf16)f1[1]; p0[6] = (bf16)f1[2]; p0[7] = (bf16)f1[3];
        p1[0] = (bf16)f2[0]; p1[1] = (bf16)f2[1]; p1[2] = (bf16)f2[2]; p1[3] = (bf16)f2[3];
        p1[4] = (bf16)f3[0]; p1[5] = (bf16)f3[1]; p1[6] = (bf16)f3[2]; p1[7] = (bf16)f3[3];
        *(bf16x8*)adst = p0;
        *(bf16x8*)(adst + 8) = p1;

        __syncthreads();

        bf16x8 af[4], bfr[4];
        for (int i = 0; i < 4; ++i)
            af[i] = *(const bf16x8*)&As[wr * 64 + i * 16 + l15][quad * 8];
        for (int j = 0; j < 4; ++j)
            bfr[j] = *(const bf16x8*)&Bs[wc * 64 + j * 16 + l15][quad * 8];
        for (int i = 0; i < 4; ++i)
            for (int j = 0; j < 4; ++j)
                acc[i][j] = __builtin_amdgcn_mfma_f32_16x16x32_bf16(
                    af[i], bfr[j], acc[i][j], 0, 0, 0);

        __syncthreads();
    }

    float bj[4];
    for (int j = 0; j < 4; ++j)
        bj[j] = bias[ntile * BN + wc * 64 + j * 16 + l15];
    for (int i = 0; i < 4; ++i) {
        int row0 = mtile * BM + wr * 64 + i * 16 + quad * 4;
        for (int r = 0; r < 4; ++r) {
            float* orow = Out + (size_t)(row0 + r) * D_DIM + ntile * BN + wc * 64 + l15;
            for (int j = 0; j < 4; ++j)
                orow[j * 16] = acc[i][j][r] + bj[j];
        }
    }
}

extern "C" void kernel_launch(void* const* d_in, const int* in_sizes, int n_in,
                              void* d_out, int out_size, void* d_ws, size_t ws_size,
                              hipStream_t stream) {
    const float* x  = (const float*)d_in[0];
    const float* W  = (const float*)d_in[1];
    const float* b  = (const float*)d_in[2];
    const float* c0 = (const float*)d_in[3];
    const float* c1 = (const float*)d_in[4];
    const float* c2 = (const float*)d_in[5];
    const float* c3 = (const float*)d_in[6];
    const float* c4 = (const float*)d_in[7];
    const float* c5 = (const float*)d_in[8];
    float* out = (float*)d_out;

    // Workspace: Weff bf16 2MB @0 | M 32KB @2MB | N 32KB @2MB+32K | Xb 32MB @4MB
    char* ws = (char*)d_ws;
    bf16*  Weff = (bf16*)ws;
    float* Mmat = (float*)(ws + 2u * 1024u * 1024u);
    float* Nmat = (float*)(ws + 2u * 1024u * 1024u + 32u * 1024u);
    bf16*  Xb   = (bf16*)(ws + 4u * 1024u * 1024u);
    const size_t need = 4u * 1024u * 1024u + (size_t)BS_ROWS * D_DIM * 2u;

    fold_cores_kernel<<<1, 256, 0, stream>>>(c0, c1, c2, c3, c4, c5, Mmat, Nmat);
    build_weff_kernel<<<1024, 256, 0, stream>>>(W, Mmat, Nmat, Weff);

    dim3 grid(BS_ROWS / BM, D_DIM / BN);
    if (ws_size >= need) {
        cast_x_kernel<<<(BS_ROWS * D_DIM) / (256 * 8), 256, 0, stream>>>(x, Xb);
        gemm_bb_kernel<<<grid, 256, 0, stream>>>(Xb, Weff, b, out);
    } else {
        gemm_bias_kernel<<<grid, 256, 0, stream>>>(x, Weff, b, out);
    }
}